// Round 11
// baseline (235.491 us; speedup 1.0000x reference)
//
#include <hip/hip_runtime.h>

#define DEVFN __device__ __forceinline__

DEVFN float sgnf(float x) { return (x > 0.f) ? 1.f : ((x < 0.f) ? -1.f : 0.f); }

// round-to-nearest-even fp32 -> bf16 bits
DEVFN unsigned short f2bf(float x) {
  unsigned int u = __float_as_uint(x);
  unsigned int r = (u + 0x7fffu + ((u >> 16) & 1u)) >> 16;
  return (unsigned short)r;
}

typedef __attribute__((ext_vector_type(8))) short short8;
typedef __attribute__((ext_vector_type(4))) float f32x4;

// ---- workspace layout ----
// double region (BN stat accumulators, 64 contention slots per channel)
#define SUM1 0        // 6*64 doubles
#define SQ1  384
#define SUM2 768      // 16*64
#define SQ2  1792
#define SUM3 2816     // 120*64
#define SQ3  10496
#define DBL_BYTES 145408  // 18176 doubles

// float region offsets (in floats, from fbase = ws + DBL_BYTES)
#define A1 0
#define C1 8
#define A2 16
#define C2 32
#define A3 48
#define C3 168
#define W2B_OFF  512     // 2400: w2 binarized, layout [ci][k][ch16]
#define WFR_OFF  3584    // conv3 weights, bf16 frag image: 102400 ushort
#define WFR2_OFF 54784   // fc1 weights, bf16 frag image: 24576 ushort
#define H1_OFF   69632                  // 8192*1176 (pooled pre-BN layer1)
#define H2_OFF   (H1_OFF + 8192*1176)   // 8192*400  (pooled pre-BN layer2)
#define Y3_OFF   (H2_OFF + 8192*400)    // 8192*120  (pre-BN layer3)

// ---------------- binarize / weight-prep ----------------
__global__ __launch_bounds__(256) void binarize_k(
    const float* __restrict__ w2, const float* __restrict__ w3,
    const float* __restrict__ f1, float* __restrict__ w2t,
    unsigned short* __restrict__ wfr, unsigned short* __restrict__ wfr2) {
  int i = blockIdx.x * 256 + threadIdx.x;
  if (i < 2400) {  // [ci][k][ch]: i = ci*400 + k*16 + ch
    int ci = i / 400, r = i - ci * 400;
    int k = r >> 4, ch = r & 15;
    w2t[i] = sgnf(w2[(ch * 6 + ci) * 25 + k]);
  }
  if (i < 102400) {  // conv3 frag image: k' = c*32 + 8g + j, k = k'>>1
    int j = i & 7;
    int t = i >> 3;
    int l = t & 63;
    int cc = (t >> 6) % 25;
    int nt = (t >> 6) / 25;
    int ch = nt * 16 + (l & 15);
    int kp = cc * 32 + ((l >> 4) << 3) + j;
    float v = (ch < 120) ? sgnf(w3[ch * 400 + (kp >> 1)]) : 0.f;
    wfr[i] = f2bf(v);  // exact for -1/0/+1
  }
  if (i < 24576) {  // fc1 frag image: 6 nt x 8 c x 64 lane x 8
    int j = i & 7;
    int t = i >> 3;
    int l = t & 63;
    int cc = (t >> 6) & 7;
    int nt = t >> 9;
    int col = nt * 16 + (l & 15);
    int kp = cc * 32 + ((l >> 4) << 3) + j;
    int k = kp >> 1;
    float v = (col < 84 && k < 120) ? sgnf(f1[col * 120 + k]) : 0.f;
    wfr2[i] = f2bf(v);
  }
}

// ---------------- layer 1 fused: conv + stats + pre-BN maxpool ----------------
__global__ __launch_bounds__(256, 3) void conv1_fused(
    const float* __restrict__ x, const float* __restrict__ w1,
    const float* __restrict__ b1, float* __restrict__ m1,
    double* __restrict__ sums) {
  __shared__ float simg[8 * 1088];   // row stride 34 (bank-conflict pad)
  __shared__ float swtp[6 * 40];     // padded weights, stride 40
  __shared__ float red[6], redq[6];
  int tid = threadIdx.x;
  int img0 = blockIdx.x * 8;
  {
    const float2* xg = (const float2*)(x + (size_t)img0 * 1024);
    for (int i2 = tid; i2 < 4096; i2 += 256) {
      int img = i2 >> 9;
      int r = (i2 >> 4) & 31;
      int c2 = i2 & 15;
      *(float2*)&simg[img * 1088 + r * 34 + c2 * 2] = xg[i2];
    }
  }
  for (int i = tid; i < 240; i += 256) {
    int ch = i / 40, k = i - ch * 40;
    swtp[i] = (k < 25) ? w1[ch * 25 + k] : 0.f;
  }
  if (tid < 6) { red[tid] = 0.f; redq[tid] = 0.f; }
  __syncthreads();

  for (int idx = tid; idx < 672; idx += 256) {
    int img = idx / 84;
    int r = idx - img * 84;
    int ch = r / 14;
    int py = r - ch * 14;
    float wr[25];
    {
      const float4* wp = (const float4*)&swtp[ch * 40];
#pragma unroll
      for (int t = 0; t < 6; ++t) {
        float4 v = wp[t];
        wr[4 * t] = v.x; wr[4 * t + 1] = v.y; wr[4 * t + 2] = v.z; wr[4 * t + 3] = v.w;
      }
      wr[24] = swtp[ch * 40 + 24];
    }
    float bb = b1[ch];
    float acc0[28], acc1[28];
#pragma unroll
    for (int o = 0; o < 28; ++o) { acc0[o] = bb; acc1[o] = bb; }
#pragma unroll
    for (int d = 0; d < 6; ++d) {
      int row = 2 * py + d;
      float rb[32];
      const float2* rp = (const float2*)&simg[img * 1088 + row * 34];
#pragma unroll
      for (int t = 0; t < 16; ++t) { float2 v = rp[t]; rb[2 * t] = v.x; rb[2 * t + 1] = v.y; }
      if (d < 5) {
#pragma unroll
        for (int kx = 0; kx < 5; ++kx) {
          float w = wr[d * 5 + kx];
#pragma unroll
          for (int o = 0; o < 28; ++o) acc0[o] = fmaf(rb[o + kx], w, acc0[o]);
        }
      }
      if (d >= 1) {
#pragma unroll
        for (int kx = 0; kx < 5; ++kx) {
          float w = wr[(d - 1) * 5 + kx];
#pragma unroll
          for (int o = 0; o < 28; ++o) acc1[o] = fmaf(rb[o + kx], w, acc1[o]);
        }
      }
    }
    float s = 0.f, s2 = 0.f;
#pragma unroll
    for (int o = 0; o < 28; ++o) {
      s += acc0[o] + acc1[o];
      s2 = fmaf(acc0[o], acc0[o], s2);
      s2 = fmaf(acc1[o], acc1[o], s2);
    }
    atomicAdd(&red[ch], s);
    atomicAdd(&redq[ch], s2);
    float* mp = m1 + (size_t)(img0 + img) * 1176 + ch * 196 + py * 14;
#pragma unroll
    for (int j = 0; j < 7; ++j) {
      float2 v;
      v.x = fmaxf(fmaxf(acc0[4 * j], acc0[4 * j + 1]), fmaxf(acc1[4 * j], acc1[4 * j + 1]));
      v.y = fmaxf(fmaxf(acc0[4 * j + 2], acc0[4 * j + 3]), fmaxf(acc1[4 * j + 2], acc1[4 * j + 3]));
      *(float2*)&mp[2 * j] = v;
    }
  }
  __syncthreads();
  if (tid < 6) {
    int slot = blockIdx.x & 63;
    atomicAdd(&sums[SUM1 + tid * 64 + slot], (double)red[tid]);
    atomicAdd(&sums[SQ1 + tid * 64 + slot], (double)redq[tid]);
  }
}

// ---------------- BN finalize: a = g*rsqrt(var+eps), c = beta - mean*a ------
__global__ __launch_bounds__(128) void finalize_bn(
    const double* __restrict__ sum, const double* __restrict__ sq, int nch,
    double invN, double eps, const float* __restrict__ gamma,
    const float* __restrict__ beta, float* __restrict__ a,
    float* __restrict__ c) {
  int ch = threadIdx.x;
  if (ch >= nch) return;
  double s = 0.0, q = 0.0;
  for (int k = 0; k < 64; ++k) {
    s += sum[ch * 64 + k];
    q += sq[ch * 64 + k];
  }
  double mean = s * invN;
  double var = q * invN - mean * mean;
  float inv = (float)(1.0 / sqrt(var + eps));
  float g = gamma ? fmaxf(gamma[ch], 0.01f) : 1.f;
  float av = g * inv;
  float cv = (beta ? beta[ch] : 0.f) - (float)mean * av;
  a[ch] = av;
  c[ch] = cv;
}

// ---------------- layer 2 fused: BN1/relu on load, conv + stats + pre-BN pool
// block 320 = 16ch x 4img x 5pr.  Weights read from GLOBAL (9.6 KB, L1-hot;
// 16 ch-lanes hit one 64B line, img-groups broadcast it) — VMEM pipe runs
// parallel to the LDS pipe, halving LDS issue vs the LDS-weight variant.
__global__ __launch_bounds__(320, 5) void conv2_fused(
    const float* __restrict__ m1, const float* __restrict__ w2t,
    const float* __restrict__ b2, const float* __restrict__ scales,
    float* __restrict__ m2, double* __restrict__ sums) {
  __shared__ float sh1[4 * 1352];   // 4 img x (6 pl x 14 rows x 16 pad) + 8
  __shared__ float sa1[6], sc1[6];
  __shared__ float red[16], redq[16];
  int tid = threadIdx.x;
  int img0 = blockIdx.x * 4;
  if (tid < 6) { sa1[tid] = scales[A1 + tid]; sc1[tid] = scales[C1 + tid]; }
  if (tid < 16) { red[tid] = 0.f; redq[tid] = 0.f; }
  __syncthreads();
  {
    const float2* mg = (const float2*)(m1 + (size_t)img0 * 1176);
    for (int i2 = tid; i2 < 2352; i2 += 320) {
      int img = i2 / 588;
      int r = i2 - img * 588;
      int pl = r / 98;
      int rr = r - pl * 98;
      int row = rr / 7, t = rr - row * 7;
      float a = sa1[pl], c = sc1[pl];
      float2 v = mg[i2];
      v.x = fmaxf(fmaf(a, v.x, c), 0.f);
      v.y = fmaxf(fmaf(a, v.y, c), 0.f);
      *(float2*)&sh1[img * 1352 + pl * 224 + row * 16 + t * 2] = v;
    }
  }
  __syncthreads();

  int ch = tid & 15;
  int img = (tid >> 4) & 3;
  int pr = tid >> 6;  // 0..4, uniform per wave
  float bb = b2[ch];
  float acc[2][10];
#pragma unroll
  for (int o = 0; o < 10; ++o) { acc[0][o] = bb; acc[1][o] = bb; }
  const float* ibase = &sh1[img * 1352];
  for (int ci = 0; ci < 6; ++ci) {
    float w[25];
    {
      const float* wg = w2t + ci * 400 + ch;  // global, L1-resident
#pragma unroll
      for (int k = 0; k < 25; ++k) w[k] = wg[k * 16];
    }
    const float* rbase = ibase + ci * 224 + pr * 32;
#pragma unroll
    for (int d = 0; d < 6; ++d) {
      float rb[16];
      const float4* rp = (const float4*)(rbase + d * 16);
#pragma unroll
      for (int t = 0; t < 4; ++t) {
        float4 v = rp[t];
        rb[4 * t] = v.x; rb[4 * t + 1] = v.y; rb[4 * t + 2] = v.z; rb[4 * t + 3] = v.w;
      }
      if (d < 5) {
#pragma unroll
        for (int kx = 0; kx < 5; ++kx) {
          float wv = w[d * 5 + kx];
#pragma unroll
          for (int o = 0; o < 10; ++o) acc[0][o] = fmaf(rb[o + kx], wv, acc[0][o]);
        }
      }
      if (d >= 1) {
#pragma unroll
        for (int kx = 0; kx < 5; ++kx) {
          float wv = w[(d - 1) * 5 + kx];
#pragma unroll
          for (int o = 0; o < 10; ++o) acc[1][o] = fmaf(rb[o + kx], wv, acc[1][o]);
        }
      }
    }
  }
  float s0 = 0.f, q0 = 0.f;
#pragma unroll
  for (int rr2 = 0; rr2 < 2; ++rr2)
#pragma unroll
    for (int o = 0; o < 10; ++o) {
      float v = acc[rr2][o];
      s0 += v;
      q0 = fmaf(v, v, q0);
    }
  {
    float* mpo = m2 + (size_t)(img0 + img) * 400 + ch * 25 + pr * 5;
#pragma unroll
    for (int pc = 0; pc < 5; ++pc)
      mpo[pc] = fmaxf(fmaxf(acc[0][2 * pc], acc[0][2 * pc + 1]),
                      fmaxf(acc[1][2 * pc], acc[1][2 * pc + 1]));
  }
  s0 += __shfl_xor(s0, 16, 64); q0 += __shfl_xor(q0, 16, 64);
  s0 += __shfl_xor(s0, 32, 64); q0 += __shfl_xor(q0, 32, 64);
  if ((tid & 48) == 0) {
    atomicAdd(&red[ch], s0);
    atomicAdd(&redq[ch], q0);
  }
  __syncthreads();
  if (tid < 16) {
    int slot = blockIdx.x & 63;
    atomicAdd(&sums[SUM2 + tid * 64 + slot], (double)red[tid]);
    atomicAdd(&sums[SQ2 + tid * 64 + slot], (double)redq[tid]);
  }
}

// ---------------- layer 3: MFMA bf16-split GEMM v2 — whole A-tile staged once
// (u32 hi|lo packed, [img][k] stride 404), barrier-free 25-chunk MFMA loop.
__global__ __launch_bounds__(256) void conv3_mfma(
    const float* __restrict__ m2, const unsigned short* __restrict__ wfr,
    const float* __restrict__ b3, const float* __restrict__ scales,
    float* __restrict__ y3, double* __restrict__ sums) {
  __shared__ unsigned int Alds[16 * 404];  // 25.9 KB
  __shared__ float sa2[16], sc2[16];
  __shared__ float red[128], redq[128];
  int tid = threadIdx.x;
  int img0 = blockIdx.x * 16;
  if (tid < 16) { sa2[tid] = scales[A2 + tid]; sc2[tid] = scales[C2 + tid]; }
  if (tid < 128) { red[tid] = 0.f; redq[tid] = 0.f; }
  __syncthreads();
  // stage: 16 imgs x 400 k, BN2+relu, hi/lo pack -> u32
  for (int i4 = tid; i4 < 1600; i4 += 256) {
    int img = i4 / 100, k4 = i4 - img * 100;
    int k = 4 * k4;
    float4 v = *(const float4*)(m2 + (size_t)(img0 + img) * 400 + k);
    float vv[4] = {v.x, v.y, v.z, v.w};
    unsigned int pk[4];
#pragma unroll
    for (int e = 0; e < 4; ++e) {
      int ch = ((k + e) * 41) >> 10;  // /25
      float val = fmaxf(fmaf(sa2[ch], vv[e], sc2[ch]), 0.f);
      unsigned int hb = f2bf(val);
      float vh = __uint_as_float(hb << 16);
      unsigned int lb = f2bf(val - vh);
      pk[e] = hb | (lb << 16);
    }
    unsigned int* dst = &Alds[img * 404 + k];
    dst[0] = pk[0]; dst[1] = pk[1]; dst[2] = pk[2]; dst[3] = pk[3];
  }
  __syncthreads();

  int lane = tid & 63;
  int wv = tid >> 6;
  int nt0 = wv * 2, nt1 = wv * 2 + 1;
  const short8* bvec = (const short8*)wfr;
  int arow = lane & 15;
  int ag = lane >> 4;
  f32x4 acc0 = {0.f, 0.f, 0.f, 0.f}, acc1 = {0.f, 0.f, 0.f, 0.f};
  const unsigned short* abase =
      (const unsigned short*)&Alds[arow * 404 + ag * 4];
#pragma unroll 5
  for (int c = 0; c < 25; ++c) {
    short8 af = *(const short8*)(abase + c * 32);  // 16B aligned
    short8 b0 = bvec[(nt0 * 25 + c) * 64 + lane];
    short8 b1 = bvec[(nt1 * 25 + c) * 64 + lane];
    acc0 = __builtin_amdgcn_mfma_f32_16x16x32_bf16(af, b0, acc0, 0, 0, 0);
    acc1 = __builtin_amdgcn_mfma_f32_16x16x32_bf16(af, b1, acc1, 0, 0, 0);
  }
  int chA = nt0 * 16 + (lane & 15);
  int chB = nt1 * 16 + (lane & 15);
  int rbase = img0 + ((lane >> 4) << 2);
  {
    float bias = b3[chA];
    float s = 0.f, q = 0.f;
#pragma unroll
    for (int r = 0; r < 4; ++r) {
      float v = acc0[r] + bias;
      y3[(size_t)(rbase + r) * 120 + chA] = v;
      s += v; q = fmaf(v, v, q);
    }
    atomicAdd(&red[chA], s);
    atomicAdd(&redq[chA], q);
  }
  if (chB < 120) {
    float bias = b3[chB];
    float s = 0.f, q = 0.f;
#pragma unroll
    for (int r = 0; r < 4; ++r) {
      float v = acc1[r] + bias;
      y3[(size_t)(rbase + r) * 120 + chB] = v;
      s += v; q = fmaf(v, v, q);
    }
    atomicAdd(&red[chB], s);
    atomicAdd(&redq[chB], q);
  }
  __syncthreads();
  if (tid < 120) {
    int slot = blockIdx.x & 63;
    atomicAdd(&sums[SUM3 + tid * 64 + slot], (double)red[tid]);
    atomicAdd(&sums[SQ3 + tid * 64 + slot], (double)redq[tid]);
  }
}

// ---------------- fc: BN3+relu -> MFMA fc1(binary, bf16-split) -> relu -> fc2
// block 192 = 3 waves x 2 N-tiles (N=96 pad, 84 valid). 16 imgs/block.
__global__ __launch_bounds__(192) void fc_mfma(
    const float* __restrict__ y3, const float* __restrict__ scales,
    const unsigned short* __restrict__ wfr2, const float* __restrict__ b1,
    const float* __restrict__ w2, const float* __restrict__ b2,
    float* __restrict__ out) {
  __shared__ unsigned int Alds[16 * 132];  // [img][k 0..127 pad] u32 hi|lo
  __shared__ float sh4[16 * 88];
  __shared__ float sw2[10 * 85];
  __shared__ float sa3[120], sc3[120];
  __shared__ float sb1[84], sb2[10];
  int tid = threadIdx.x;
  int img0 = blockIdx.x * 16;
  if (tid < 120) { sa3[tid] = scales[A3 + tid]; sc3[tid] = scales[C3 + tid]; }
  if (tid < 84) sb1[tid] = b1[tid];
  if (tid >= 84 && tid < 94) sb2[tid - 84] = b2[tid - 84];
  for (int i = tid; i < 850; i += 192) {
    int o = i / 85, k = i - o * 85;
    sw2[i] = (k < 84) ? w2[o * 84 + k] : 0.f;
  }
  __syncthreads();
  // stage: 16 imgs x 128 k (120 valid, pad zero), BN3+relu, hi/lo pack
  for (int i4 = tid; i4 < 512; i4 += 192) {
    int img = i4 >> 5, k4 = i4 & 31;
    int k = 4 * k4;
    unsigned int pk[4] = {0u, 0u, 0u, 0u};
    if (k4 < 30) {
      float4 v = *(const float4*)(y3 + (size_t)(img0 + img) * 120 + k);
      float vv[4] = {v.x, v.y, v.z, v.w};
#pragma unroll
      for (int e = 0; e < 4; ++e) {
        float val = fmaxf(fmaf(sa3[k + e], vv[e], sc3[k + e]), 0.f);
        unsigned int hb = f2bf(val);
        float vh = __uint_as_float(hb << 16);
        unsigned int lb = f2bf(val - vh);
        pk[e] = hb | (lb << 16);
      }
    }
    unsigned int* dst = &Alds[img * 132 + k];
    dst[0] = pk[0]; dst[1] = pk[1]; dst[2] = pk[2]; dst[3] = pk[3];
  }
  __syncthreads();

  int lane = tid & 63;
  int wv = tid >> 6;  // 0..2
  int nt0 = wv * 2, nt1 = wv * 2 + 1;
  const short8* bvec = (const short8*)wfr2;
  int arow = lane & 15;
  int ag = lane >> 4;
  f32x4 acc0 = {0.f, 0.f, 0.f, 0.f}, acc1 = {0.f, 0.f, 0.f, 0.f};
  const unsigned short* abase =
      (const unsigned short*)&Alds[arow * 132 + ag * 4];
#pragma unroll
  for (int c = 0; c < 8; ++c) {
    short8 af = *(const short8*)(abase + c * 32);
    short8 b0 = bvec[(nt0 * 8 + c) * 64 + lane];
    short8 b1 = bvec[(nt1 * 8 + c) * 64 + lane];
    acc0 = __builtin_amdgcn_mfma_f32_16x16x32_bf16(af, b0, acc0, 0, 0, 0);
    acc1 = __builtin_amdgcn_mfma_f32_16x16x32_bf16(af, b1, acc1, 0, 0, 0);
  }
  // h4 = relu(fc1 + b1) into LDS
  {
    int jA = nt0 * 16 + (lane & 15);  // <= 79, always valid
    int jB = nt1 * 16 + (lane & 15);  // may exceed 83
    int r0 = (lane >> 4) << 2;
#pragma unroll
    for (int r = 0; r < 4; ++r)
      sh4[(r0 + r) * 88 + jA] = fmaxf(acc0[r] + sb1[jA], 0.f);
    if (jB < 84) {
#pragma unroll
      for (int r = 0; r < 4; ++r)
        sh4[(r0 + r) * 88 + jB] = fmaxf(acc1[r] + sb1[jB], 0.f);
    }
  }
  __syncthreads();
  // fc2: 160 threads, one (img, out) each
  if (tid < 160) {
    int img = tid / 10, o = tid - (tid / 10) * 10;
    float acc = sb2[o];
    const float* hp = &sh4[img * 88];
    const float* wp = &sw2[o * 85];
#pragma unroll 4
    for (int k = 0; k < 84; ++k) acc = fmaf(hp[k], wp[k], acc);
    out[(size_t)(img0 + img) * 10 + o] = acc;
  }
}

extern "C" void kernel_launch(void* const* d_in, const int* in_sizes, int n_in,
                              void* d_out, int out_size, void* d_ws,
                              size_t ws_size, hipStream_t stream) {
  const float* x = (const float*)d_in[0];
  const float* conv1_w = (const float*)d_in[1];
  const float* conv1_b = (const float*)d_in[2];
  const float* conv2_w = (const float*)d_in[3];
  const float* conv2_b = (const float*)d_in[4];
  const float* bn2_g = (const float*)d_in[5];
  const float* bn2_b = (const float*)d_in[6];
  const float* conv3_w = (const float*)d_in[7];
  const float* conv3_b = (const float*)d_in[8];
  const float* bn3_g = (const float*)d_in[9];
  const float* bn3_b = (const float*)d_in[10];
  const float* fc1_w = (const float*)d_in[11];
  const float* fc1_b = (const float*)d_in[12];
  const float* fc2_w = (const float*)d_in[13];
  const float* fc2_b = (const float*)d_in[14];
  float* out = (float*)d_out;

  double* sums = (double*)d_ws;
  float* fbase = (float*)((char*)d_ws + DBL_BYTES);
  float* scales = fbase;
  float* w2t = fbase + W2B_OFF;
  unsigned short* wfr = (unsigned short*)(fbase + WFR_OFF);
  unsigned short* wfr2 = (unsigned short*)(fbase + WFR2_OFF);
  float* m1 = fbase + H1_OFF;
  float* m2 = fbase + H2_OFF;
  float* y3 = fbase + Y3_OFF;

  hipMemsetAsync(d_ws, 0, DBL_BYTES, stream);
  binarize_k<<<400, 256, 0, stream>>>(conv2_w, conv3_w, fc1_w, w2t, wfr, wfr2);

  conv1_fused<<<1024, 256, 0, stream>>>(x, conv1_w, conv1_b, m1, sums);
  finalize_bn<<<1, 128, 0, stream>>>(sums + SUM1, sums + SQ1, 6,
                                     1.0 / (8192.0 * 784.0), 1e-4, nullptr,
                                     nullptr, scales + A1, scales + C1);

  conv2_fused<<<2048, 320, 0, stream>>>(m1, w2t, conv2_b, scales, m2, sums);
  finalize_bn<<<1, 128, 0, stream>>>(sums + SUM2, sums + SQ2, 16,
                                     1.0 / (8192.0 * 100.0), 1e-4, bn2_g, bn2_b,
                                     scales + A2, scales + C2);

  conv3_mfma<<<512, 256, 0, stream>>>(m2, wfr, conv3_b, scales, y3, sums);
  finalize_bn<<<1, 128, 0, stream>>>(sums + SUM3, sums + SQ3, 120,
                                     1.0 / 8192.0, 1e-5, bn3_g, bn3_b,
                                     scales + A3, scales + C3);

  fc_mfma<<<512, 192, 0, stream>>>(y3, scales, wfr2, fc1_b, fc2_w, fc2_b, out);
}

// Round 12
// 222.901 us; speedup vs baseline: 1.0565x; 1.0565x over previous
//
#include <hip/hip_runtime.h>

#define DEVFN __device__ __forceinline__

DEVFN float sgnf(float x) { return (x > 0.f) ? 1.f : ((x < 0.f) ? -1.f : 0.f); }

// round-to-nearest-even fp32 -> bf16 bits
DEVFN unsigned short f2bf(float x) {
  unsigned int u = __float_as_uint(x);
  unsigned int r = (u + 0x7fffu + ((u >> 16) & 1u)) >> 16;
  return (unsigned short)r;
}

typedef __attribute__((ext_vector_type(8))) short short8;
typedef __attribute__((ext_vector_type(4))) float f32x4;

// ---- workspace layout ----
// double region (BN stat accumulators, 64 contention slots per channel)
#define SUM1 0        // 6*64 doubles
#define SQ1  384
#define SUM2 768      // 16*64
#define SQ2  1792
#define SUM3 2816     // 120*64
#define SQ3  10496
#define DBL_BYTES 145408  // 18176 doubles

// float region offsets (in floats, from fbase = ws + DBL_BYTES)
#define A1 0
#define C1 8
#define A2 16
#define C2 32
#define A3 48
#define C3 168
#define W2B_OFF  512     // 2400: w2 binarized, layout [ci][k][ch16]
#define WFR_OFF  3584    // conv3 weights, bf16 frag image: 102400 ushort
#define WFR2_OFF 54784   // fc1 weights, bf16 frag image: 24576 ushort
#define H1_OFF   69632                  // 8192*1176 (pooled pre-BN layer1)
#define H2_OFF   (H1_OFF + 8192*1176)   // 8192*400  (pooled pre-BN layer2)
#define Y3_OFF   (H2_OFF + 8192*400)    // 8192*120  (pre-BN layer3)

// ---------------- layer 1 fused + weight-prep tail blocks ------------------
// blocks [0,1024): conv1 (conv + stats + pre-BN maxpool)
// blocks [1024,1424): binarize/frag-image prep (no barriers, straight-line)
__global__ __launch_bounds__(256, 3) void conv1_prep(
    const float* __restrict__ x, const float* __restrict__ w1,
    const float* __restrict__ b1, float* __restrict__ m1,
    double* __restrict__ sums, const float* __restrict__ w2,
    const float* __restrict__ w3, const float* __restrict__ f1,
    float* __restrict__ w2t, unsigned short* __restrict__ wfr,
    unsigned short* __restrict__ wfr2) {
  __shared__ float simg[8 * 1088];   // row stride 34 (bank-conflict pad)
  __shared__ float swtp[6 * 40];     // padded weights, stride 40
  __shared__ float red[6], redq[6];
  int tid = threadIdx.x;
  if (blockIdx.x >= 1024) {  // ---- prep path ----
    int i = (blockIdx.x - 1024) * 256 + tid;
    if (i < 2400) {  // [ci][k][ch]: i = ci*400 + k*16 + ch
      int ci = i / 400, r = i - ci * 400;
      int k = r >> 4, ch = r & 15;
      w2t[i] = sgnf(w2[(ch * 6 + ci) * 25 + k]);
    }
    if (i < 102400) {  // conv3 frag image: k' = c*32 + 8g + j, k = k'>>1
      int j = i & 7;
      int t = i >> 3;
      int l = t & 63;
      int cc = (t >> 6) % 25;
      int nt = (t >> 6) / 25;
      int ch = nt * 16 + (l & 15);
      int kp = cc * 32 + ((l >> 4) << 3) + j;
      float v = (ch < 120) ? sgnf(w3[ch * 400 + (kp >> 1)]) : 0.f;
      wfr[i] = f2bf(v);  // exact for -1/0/+1
    }
    if (i < 24576) {  // fc1 frag image: 6 nt x 8 c x 64 lane x 8
      int j = i & 7;
      int t = i >> 3;
      int l = t & 63;
      int cc = (t >> 6) & 7;
      int nt = t >> 9;
      int col = nt * 16 + (l & 15);
      int kp = cc * 32 + ((l >> 4) << 3) + j;
      int k = kp >> 1;
      float v = (col < 84 && k < 120) ? sgnf(f1[col * 120 + k]) : 0.f;
      wfr2[i] = f2bf(v);
    }
    return;
  }
  // ---- conv1 path ----
  int img0 = blockIdx.x * 8;
  {
    const float2* xg = (const float2*)(x + (size_t)img0 * 1024);
    for (int i2 = tid; i2 < 4096; i2 += 256) {
      int img = i2 >> 9;
      int r = (i2 >> 4) & 31;
      int c2 = i2 & 15;
      *(float2*)&simg[img * 1088 + r * 34 + c2 * 2] = xg[i2];
    }
  }
  for (int i = tid; i < 240; i += 256) {
    int ch = i / 40, k = i - ch * 40;
    swtp[i] = (k < 25) ? w1[ch * 25 + k] : 0.f;
  }
  if (tid < 6) { red[tid] = 0.f; redq[tid] = 0.f; }
  __syncthreads();

  for (int idx = tid; idx < 672; idx += 256) {
    int img = idx / 84;
    int r = idx - img * 84;
    int ch = r / 14;
    int py = r - ch * 14;
    float wr[25];
    {
      const float4* wp = (const float4*)&swtp[ch * 40];
#pragma unroll
      for (int t = 0; t < 6; ++t) {
        float4 v = wp[t];
        wr[4 * t] = v.x; wr[4 * t + 1] = v.y; wr[4 * t + 2] = v.z; wr[4 * t + 3] = v.w;
      }
      wr[24] = swtp[ch * 40 + 24];
    }
    float bb = b1[ch];
    float acc0[28], acc1[28];
#pragma unroll
    for (int o = 0; o < 28; ++o) { acc0[o] = bb; acc1[o] = bb; }
#pragma unroll
    for (int d = 0; d < 6; ++d) {
      int row = 2 * py + d;
      float rb[32];
      const float2* rp = (const float2*)&simg[img * 1088 + row * 34];
#pragma unroll
      for (int t = 0; t < 16; ++t) { float2 v = rp[t]; rb[2 * t] = v.x; rb[2 * t + 1] = v.y; }
      if (d < 5) {
#pragma unroll
        for (int kx = 0; kx < 5; ++kx) {
          float w = wr[d * 5 + kx];
#pragma unroll
          for (int o = 0; o < 28; ++o) acc0[o] = fmaf(rb[o + kx], w, acc0[o]);
        }
      }
      if (d >= 1) {
#pragma unroll
        for (int kx = 0; kx < 5; ++kx) {
          float w = wr[(d - 1) * 5 + kx];
#pragma unroll
          for (int o = 0; o < 28; ++o) acc1[o] = fmaf(rb[o + kx], w, acc1[o]);
        }
      }
    }
    float s = 0.f, s2 = 0.f;
#pragma unroll
    for (int o = 0; o < 28; ++o) {
      s += acc0[o] + acc1[o];
      s2 = fmaf(acc0[o], acc0[o], s2);
      s2 = fmaf(acc1[o], acc1[o], s2);
    }
    atomicAdd(&red[ch], s);
    atomicAdd(&redq[ch], s2);
    float* mp = m1 + (size_t)(img0 + img) * 1176 + ch * 196 + py * 14;
#pragma unroll
    for (int j = 0; j < 7; ++j) {
      float2 v;
      v.x = fmaxf(fmaxf(acc0[4 * j], acc0[4 * j + 1]), fmaxf(acc1[4 * j], acc1[4 * j + 1]));
      v.y = fmaxf(fmaxf(acc0[4 * j + 2], acc0[4 * j + 3]), fmaxf(acc1[4 * j + 2], acc1[4 * j + 3]));
      *(float2*)&mp[2 * j] = v;
    }
  }
  __syncthreads();
  if (tid < 6) {
    int slot = blockIdx.x & 63;
    atomicAdd(&sums[SUM1 + tid * 64 + slot], (double)red[tid]);
    atomicAdd(&sums[SQ1 + tid * 64 + slot], (double)redq[tid]);
  }
}

// ---------------- BN finalize (parallel): wave per channel, coalesced ------
__global__ __launch_bounds__(256) void finalize_bn(
    const double* __restrict__ sum, const double* __restrict__ sq, int nch,
    double invN, double eps, const float* __restrict__ gamma,
    const float* __restrict__ beta, float* __restrict__ a,
    float* __restrict__ c) {
  int t = blockIdx.x * 256 + threadIdx.x;
  int ch = t >> 6, slot = t & 63;
  if (ch >= nch) return;
  double s = sum[ch * 64 + slot];
  double q = sq[ch * 64 + slot];
#pragma unroll
  for (int off = 32; off > 0; off >>= 1) {
    s += __shfl_down(s, off, 64);
    q += __shfl_down(q, off, 64);
  }
  if (slot == 0) {
    double mean = s * invN;
    double var = q * invN - mean * mean;
    float inv = (float)(1.0 / sqrt(var + eps));
    float g = gamma ? fmaxf(gamma[ch], 0.01f) : 1.f;
    float av = g * inv;
    float cv = (beta ? beta[ch] : 0.f) - (float)mean * av;
    a[ch] = av;
    c[ch] = cv;
  }
}

// ---------------- layer 2 fused (measured best): BN1/relu on load,
// conv + stats + pre-BN pool. block 320 = 16ch x 4img x 5pr, LDS weights.
__global__ __launch_bounds__(320, 5) void conv2_fused(
    const float* __restrict__ m1, const float* __restrict__ w2t,
    const float* __restrict__ b2, const float* __restrict__ scales,
    float* __restrict__ m2, double* __restrict__ sums) {
  __shared__ float sh1[4 * 1352];   // 4 img x (6 pl x 14 rows x 16 pad) + 8
  __shared__ float swt[2400];       // [ci][k][ch16]
  __shared__ float sa1[6], sc1[6];
  __shared__ float red[16], redq[16];
  int tid = threadIdx.x;
  int img0 = blockIdx.x * 4;
  if (tid < 6) { sa1[tid] = scales[A1 + tid]; sc1[tid] = scales[C1 + tid]; }
  if (tid < 16) { red[tid] = 0.f; redq[tid] = 0.f; }
  __syncthreads();
  {
    const float4* wg = (const float4*)w2t;
    float4* w4 = (float4*)swt;
    for (int i4 = tid; i4 < 600; i4 += 320) w4[i4] = wg[i4];
  }
  {
    const float2* mg = (const float2*)(m1 + (size_t)img0 * 1176);
    for (int i2 = tid; i2 < 2352; i2 += 320) {
      int img = i2 / 588;
      int r = i2 - img * 588;
      int pl = r / 98;
      int rr = r - pl * 98;
      int row = rr / 7, t = rr - row * 7;
      float a = sa1[pl], c = sc1[pl];
      float2 v = mg[i2];
      v.x = fmaxf(fmaf(a, v.x, c), 0.f);
      v.y = fmaxf(fmaf(a, v.y, c), 0.f);
      *(float2*)&sh1[img * 1352 + pl * 224 + row * 16 + t * 2] = v;
    }
  }
  __syncthreads();

  int ch = tid & 15;
  int img = (tid >> 4) & 3;
  int pr = tid >> 6;  // 0..4, uniform per wave
  float bb = b2[ch];
  float acc[2][10];
#pragma unroll
  for (int o = 0; o < 10; ++o) { acc[0][o] = bb; acc[1][o] = bb; }
  const float* ibase = &sh1[img * 1352];
  for (int ci = 0; ci < 6; ++ci) {
    float w[25];
#pragma unroll
    for (int k = 0; k < 25; ++k) w[k] = swt[ci * 400 + k * 16 + ch];
    const float* rbase = ibase + ci * 224 + pr * 32;
#pragma unroll
    for (int d = 0; d < 6; ++d) {
      float rb[16];
      const float4* rp = (const float4*)(rbase + d * 16);
#pragma unroll
      for (int t = 0; t < 4; ++t) {
        float4 v = rp[t];
        rb[4 * t] = v.x; rb[4 * t + 1] = v.y; rb[4 * t + 2] = v.z; rb[4 * t + 3] = v.w;
      }
      if (d < 5) {
#pragma unroll
        for (int kx = 0; kx < 5; ++kx) {
          float wv = w[d * 5 + kx];
#pragma unroll
          for (int o = 0; o < 10; ++o) acc[0][o] = fmaf(rb[o + kx], wv, acc[0][o]);
        }
      }
      if (d >= 1) {
#pragma unroll
        for (int kx = 0; kx < 5; ++kx) {
          float wv = w[(d - 1) * 5 + kx];
#pragma unroll
          for (int o = 0; o < 10; ++o) acc[1][o] = fmaf(rb[o + kx], wv, acc[1][o]);
        }
      }
    }
  }
  float s0 = 0.f, q0 = 0.f;
#pragma unroll
  for (int rr2 = 0; rr2 < 2; ++rr2)
#pragma unroll
    for (int o = 0; o < 10; ++o) {
      float v = acc[rr2][o];
      s0 += v;
      q0 = fmaf(v, v, q0);
    }
  {
    float* mpo = m2 + (size_t)(img0 + img) * 400 + ch * 25 + pr * 5;
#pragma unroll
    for (int pc = 0; pc < 5; ++pc)
      mpo[pc] = fmaxf(fmaxf(acc[0][2 * pc], acc[0][2 * pc + 1]),
                      fmaxf(acc[1][2 * pc], acc[1][2 * pc + 1]));
  }
  s0 += __shfl_xor(s0, 16, 64); q0 += __shfl_xor(q0, 16, 64);
  s0 += __shfl_xor(s0, 32, 64); q0 += __shfl_xor(q0, 32, 64);
  if ((tid & 48) == 0) {
    atomicAdd(&red[ch], s0);
    atomicAdd(&redq[ch], q0);
  }
  __syncthreads();
  if (tid < 16) {
    int slot = blockIdx.x & 63;
    atomicAdd(&sums[SUM2 + tid * 64 + slot], (double)red[tid]);
    atomicAdd(&sums[SQ2 + tid * 64 + slot], (double)redq[tid]);
  }
}

// ---------------- layer 3: MFMA bf16-split GEMM — whole A-tile staged once
// (u32 hi|lo packed, [img][k] stride 404), barrier-free 25-chunk MFMA loop.
__global__ __launch_bounds__(256) void conv3_mfma(
    const float* __restrict__ m2, const unsigned short* __restrict__ wfr,
    const float* __restrict__ b3, const float* __restrict__ scales,
    float* __restrict__ y3, double* __restrict__ sums) {
  __shared__ unsigned int Alds[16 * 404];  // 25.9 KB
  __shared__ float sa2[16], sc2[16];
  __shared__ float red[128], redq[128];
  int tid = threadIdx.x;
  int img0 = blockIdx.x * 16;
  if (tid < 16) { sa2[tid] = scales[A2 + tid]; sc2[tid] = scales[C2 + tid]; }
  if (tid < 128) { red[tid] = 0.f; redq[tid] = 0.f; }
  __syncthreads();
  // stage: 16 imgs x 400 k, BN2+relu, hi/lo pack -> u32
  for (int i4 = tid; i4 < 1600; i4 += 256) {
    int img = i4 / 100, k4 = i4 - img * 100;
    int k = 4 * k4;
    float4 v = *(const float4*)(m2 + (size_t)(img0 + img) * 400 + k);
    float vv[4] = {v.x, v.y, v.z, v.w};
    unsigned int pk[4];
#pragma unroll
    for (int e = 0; e < 4; ++e) {
      int ch = ((k + e) * 41) >> 10;  // /25
      float val = fmaxf(fmaf(sa2[ch], vv[e], sc2[ch]), 0.f);
      unsigned int hb = f2bf(val);
      float vh = __uint_as_float(hb << 16);
      unsigned int lb = f2bf(val - vh);
      pk[e] = hb | (lb << 16);
    }
    unsigned int* dst = &Alds[img * 404 + k];
    dst[0] = pk[0]; dst[1] = pk[1]; dst[2] = pk[2]; dst[3] = pk[3];
  }
  __syncthreads();

  int lane = tid & 63;
  int wv = tid >> 6;
  int nt0 = wv * 2, nt1 = wv * 2 + 1;
  const short8* bvec = (const short8*)wfr;
  int arow = lane & 15;
  int ag = lane >> 4;
  f32x4 acc0 = {0.f, 0.f, 0.f, 0.f}, acc1 = {0.f, 0.f, 0.f, 0.f};
  const unsigned short* abase =
      (const unsigned short*)&Alds[arow * 404 + ag * 4];
#pragma unroll 5
  for (int c = 0; c < 25; ++c) {
    short8 af = *(const short8*)(abase + c * 32);  // 16B aligned
    short8 b0 = bvec[(nt0 * 25 + c) * 64 + lane];
    short8 b1 = bvec[(nt1 * 25 + c) * 64 + lane];
    acc0 = __builtin_amdgcn_mfma_f32_16x16x32_bf16(af, b0, acc0, 0, 0, 0);
    acc1 = __builtin_amdgcn_mfma_f32_16x16x32_bf16(af, b1, acc1, 0, 0, 0);
  }
  int chA = nt0 * 16 + (lane & 15);
  int chB = nt1 * 16 + (lane & 15);
  int rbase = img0 + ((lane >> 4) << 2);
  {
    float bias = b3[chA];
    float s = 0.f, q = 0.f;
#pragma unroll
    for (int r = 0; r < 4; ++r) {
      float v = acc0[r] + bias;
      y3[(size_t)(rbase + r) * 120 + chA] = v;
      s += v; q = fmaf(v, v, q);
    }
    atomicAdd(&red[chA], s);
    atomicAdd(&redq[chA], q);
  }
  if (chB < 120) {
    float bias = b3[chB];
    float s = 0.f, q = 0.f;
#pragma unroll
    for (int r = 0; r < 4; ++r) {
      float v = acc1[r] + bias;
      y3[(size_t)(rbase + r) * 120 + chB] = v;
      s += v; q = fmaf(v, v, q);
    }
    atomicAdd(&red[chB], s);
    atomicAdd(&redq[chB], q);
  }
  __syncthreads();
  if (tid < 120) {
    int slot = blockIdx.x & 63;
    atomicAdd(&sums[SUM3 + tid * 64 + slot], (double)red[tid]);
    atomicAdd(&sums[SQ3 + tid * 64 + slot], (double)redq[tid]);
  }
}

// ---------------- fc: BN3+relu -> MFMA fc1(binary, bf16-split) -> relu -> fc2
// block 192 = 3 waves x 2 N-tiles (N=96 pad, 84 valid). 16 imgs/block.
__global__ __launch_bounds__(192) void fc_mfma(
    const float* __restrict__ y3, const float* __restrict__ scales,
    const unsigned short* __restrict__ wfr2, const float* __restrict__ b1,
    const float* __restrict__ w2, const float* __restrict__ b2,
    float* __restrict__ out) {
  __shared__ unsigned int Alds[16 * 132];  // [img][k 0..127 pad] u32 hi|lo
  __shared__ float sh4[16 * 88];
  __shared__ float sw2[10 * 85];
  __shared__ float sa3[120], sc3[120];
  __shared__ float sb1[84], sb2[10];
  int tid = threadIdx.x;
  int img0 = blockIdx.x * 16;
  if (tid < 120) { sa3[tid] = scales[A3 + tid]; sc3[tid] = scales[C3 + tid]; }
  if (tid < 84) sb1[tid] = b1[tid];
  if (tid >= 84 && tid < 94) sb2[tid - 84] = b2[tid - 84];
  for (int i = tid; i < 850; i += 192) {
    int o = i / 85, k = i - o * 85;
    sw2[i] = (k < 84) ? w2[o * 84 + k] : 0.f;
  }
  __syncthreads();
  // stage: 16 imgs x 128 k (120 valid, pad zero), BN3+relu, hi/lo pack
  for (int i4 = tid; i4 < 512; i4 += 192) {
    int img = i4 >> 5, k4 = i4 & 31;
    int k = 4 * k4;
    unsigned int pk[4] = {0u, 0u, 0u, 0u};
    if (k4 < 30) {
      float4 v = *(const float4*)(y3 + (size_t)(img0 + img) * 120 + k);
      float vv[4] = {v.x, v.y, v.z, v.w};
#pragma unroll
      for (int e = 0; e < 4; ++e) {
        float val = fmaxf(fmaf(sa3[k + e], vv[e], sc3[k + e]), 0.f);
        unsigned int hb = f2bf(val);
        float vh = __uint_as_float(hb << 16);
        unsigned int lb = f2bf(val - vh);
        pk[e] = hb | (lb << 16);
      }
    }
    unsigned int* dst = &Alds[img * 132 + k];
    dst[0] = pk[0]; dst[1] = pk[1]; dst[2] = pk[2]; dst[3] = pk[3];
  }
  __syncthreads();

  int lane = tid & 63;
  int wv = tid >> 6;  // 0..2
  int nt0 = wv * 2, nt1 = wv * 2 + 1;
  const short8* bvec = (const short8*)wfr2;
  int arow = lane & 15;
  int ag = lane >> 4;
  f32x4 acc0 = {0.f, 0.f, 0.f, 0.f}, acc1 = {0.f, 0.f, 0.f, 0.f};
  const unsigned short* abase =
      (const unsigned short*)&Alds[arow * 132 + ag * 4];
#pragma unroll
  for (int c = 0; c < 8; ++c) {
    short8 af = *(const short8*)(abase + c * 32);
    short8 b0 = bvec[(nt0 * 8 + c) * 64 + lane];
    short8 b1 = bvec[(nt1 * 8 + c) * 64 + lane];
    acc0 = __builtin_amdgcn_mfma_f32_16x16x32_bf16(af, b0, acc0, 0, 0, 0);
    acc1 = __builtin_amdgcn_mfma_f32_16x16x32_bf16(af, b1, acc1, 0, 0, 0);
  }
  // h4 = relu(fc1 + b1) into LDS
  {
    int jA = nt0 * 16 + (lane & 15);  // <= 79, always valid
    int jB = nt1 * 16 + (lane & 15);  // may exceed 83
    int r0 = (lane >> 4) << 2;
#pragma unroll
    for (int r = 0; r < 4; ++r)
      sh4[(r0 + r) * 88 + jA] = fmaxf(acc0[r] + sb1[jA], 0.f);
    if (jB < 84) {
#pragma unroll
      for (int r = 0; r < 4; ++r)
        sh4[(r0 + r) * 88 + jB] = fmaxf(acc1[r] + sb1[jB], 0.f);
    }
  }
  __syncthreads();
  // fc2: 160 threads, one (img, out) each
  if (tid < 160) {
    int img = tid / 10, o = tid - (tid / 10) * 10;
    float acc = sb2[o];
    const float* hp = &sh4[img * 88];
    const float* wp = &sw2[o * 85];
#pragma unroll 4
    for (int k = 0; k < 84; ++k) acc = fmaf(hp[k], wp[k], acc);
    out[(size_t)(img0 + img) * 10 + o] = acc;
  }
}

extern "C" void kernel_launch(void* const* d_in, const int* in_sizes, int n_in,
                              void* d_out, int out_size, void* d_ws,
                              size_t ws_size, hipStream_t stream) {
  const float* x = (const float*)d_in[0];
  const float* conv1_w = (const float*)d_in[1];
  const float* conv1_b = (const float*)d_in[2];
  const float* conv2_w = (const float*)d_in[3];
  const float* conv2_b = (const float*)d_in[4];
  const float* bn2_g = (const float*)d_in[5];
  const float* bn2_b = (const float*)d_in[6];
  const float* conv3_w = (const float*)d_in[7];
  const float* conv3_b = (const float*)d_in[8];
  const float* bn3_g = (const float*)d_in[9];
  const float* bn3_b = (const float*)d_in[10];
  const float* fc1_w = (const float*)d_in[11];
  const float* fc1_b = (const float*)d_in[12];
  const float* fc2_w = (const float*)d_in[13];
  const float* fc2_b = (const float*)d_in[14];
  float* out = (float*)d_out;

  double* sums = (double*)d_ws;
  float* fbase = (float*)((char*)d_ws + DBL_BYTES);
  float* scales = fbase;
  float* w2t = fbase + W2B_OFF;
  unsigned short* wfr = (unsigned short*)(fbase + WFR_OFF);
  unsigned short* wfr2 = (unsigned short*)(fbase + WFR2_OFF);
  float* m1 = fbase + H1_OFF;
  float* m2 = fbase + H2_OFF;
  float* y3 = fbase + Y3_OFF;

  hipMemsetAsync(d_ws, 0, DBL_BYTES, stream);

  conv1_prep<<<1424, 256, 0, stream>>>(x, conv1_w, conv1_b, m1, sums, conv2_w,
                                       conv3_w, fc1_w, w2t, wfr, wfr2);
  finalize_bn<<<2, 256, 0, stream>>>(sums + SUM1, sums + SQ1, 6,
                                     1.0 / (8192.0 * 784.0), 1e-4, nullptr,
                                     nullptr, scales + A1, scales + C1);

  conv2_fused<<<2048, 320, 0, stream>>>(m1, w2t, conv2_b, scales, m2, sums);
  finalize_bn<<<4, 256, 0, stream>>>(sums + SUM2, sums + SQ2, 16,
                                     1.0 / (8192.0 * 100.0), 1e-4, bn2_g, bn2_b,
                                     scales + A2, scales + C2);

  conv3_mfma<<<512, 256, 0, stream>>>(m2, wfr, conv3_b, scales, y3, sums);
  finalize_bn<<<30, 256, 0, stream>>>(sums + SUM3, sums + SQ3, 120,
                                      1.0 / 8192.0, 1e-5, bn3_g, bn3_b,
                                      scales + A3, scales + C3);

  fc_mfma<<<512, 192, 0, stream>>>(y3, scales, wfr2, fc1_b, fc2_w, fc2_b, out);
}